// Round 3
// baseline (4430.158 us; speedup 1.0000x reference)
//
#include <hip/hip_runtime.h>

#define NN 30000
#define EE 480000

// ---------- zero-fill fallback (ws too small diagnostic) ----------
__global__ __launch_bounds__(256) void k_zero(float* __restrict__ out, int n){
  int i = blockIdx.x*256 + threadIdx.x;
  if (i < n) out[i] = 0.f;
}

// ---------- node feature init: fA[N][288] (row0=node_l0, rest 0), hist=0 ----------
__global__ __launch_bounds__(256) void k_init(
    const float* __restrict__ nl0, float* __restrict__ fA, int* __restrict__ hist)
{
  int i = blockIdx.x*256 + threadIdx.x;   // exactly N*288
  int n = i/288; int r2 = i - n*288;
  fA[i] = (r2 < 32) ? nl0[(size_t)n*32 + r2] : 0.f;
  if (i < NN) hist[i] = 0;
}

__global__ __launch_bounds__(256) void k_hist(const int* __restrict__ dst, int* __restrict__ hist){
  int e = blockIdx.x*256 + threadIdx.x;
  if (e < EE) atomicAdd(&hist[dst[e]], 1);
}

// single-block exclusive scan over hist[NN] -> offs, cursor
__global__ void k_scan(const int* __restrict__ hist, int* __restrict__ offs,
                       int* __restrict__ cursor, int n)
{
  __shared__ int sm[1024];
  __shared__ int carry;
  int tid = threadIdx.x;
  if (tid==0) carry = 0;
  __syncthreads();
  for (int base=0; base<n; base+=1024){
    int i = base + tid;
    int v = (i<n)? hist[i] : 0;
    sm[tid] = v; __syncthreads();
    for (int o=1;o<1024;o<<=1){
      int tv = (tid>=o)? sm[tid-o] : 0;
      __syncthreads();
      sm[tid] += tv;
      __syncthreads();
    }
    int cy = carry;
    int excl = sm[tid] - v;
    if (i<n){ offs[i] = cy+excl; cursor[i] = cy+excl; }
    __syncthreads();
    if (tid==1023) carry = cy + sm[1023];
    __syncthreads();
  }
  if (tid==0) offs[n] = carry;
}

__global__ __launch_bounds__(256) void k_scatter(const int* __restrict__ dst,
    int* __restrict__ cursor, int* __restrict__ perm)
{
  int e = blockIdx.x*256 + threadIdx.x;
  if (e >= EE) return;
  int d = dst[e];
  int p = atomicAdd(&cursor[d], 1);
  perm[p] = e;
}

// ---------- per-node q projection folded into T: T[n][h][ci] = sum_o Wk[ci][h*8+o]*q[n][h*8+o] ----------
// logits_h(edge) = sum_ci m0[ci]*T[d][h][ci]  (eliminates per-edge k-projection)
__global__ __launch_bounds__(256) void k_qt(
    const float* __restrict__ f_in, const float* __restrict__ Wqf,
    const float* __restrict__ Wkf, float* __restrict__ Tq)
{
  __shared__ float WqL[1024];
  __shared__ float WkL[1056];           // [c][33] padded: bank-conflict-free row reads
  int tid = threadIdx.x;
  for (int i=tid;i<1024;i+=256) WqL[i]=Wqf[i];
  for (int i=tid;i<1056;i+=256){ int r=i/33, o=i-r*33; if (o<32) WkL[i]=Wkf[r*32+o]; }
  __syncthreads();
  int n = blockIdx.x*8 + (tid>>5), c = tid&31;
  const float* f0 = f_in + (size_t)n*288;
  float q=0.f;
  #pragma unroll
  for (int ci=0;ci<32;ci++) q = fmaf(f0[ci], WqL[ci*32+c], q);
  float t0=0.f,t1=0.f,t2=0.f,t3=0.f;
  #pragma unroll
  for (int j=0;j<32;j++){
    float qb = __shfl(q, j, 32);
    float wv = WkL[c*33 + j];
    if (j<8)       t0 = fmaf(wv, qb, t0);
    else if (j<16) t1 = fmaf(wv, qb, t1);
    else if (j<24) t2 = fmaf(wv, qb, t2);
    else           t3 = fmaf(wv, qb, t3);
  }
  float* T = Tq + (size_t)n*128;
  T[c]=t0; T[32+c]=t1; T[64+c]=t2; T[96+c]=t3;
}

// ---------- zero agg buffer + den ----------
__global__ __launch_bounds__(256) void k_zeroagg(float* __restrict__ fo, float* __restrict__ den){
  int i = blockIdx.x*256 + threadIdx.x;   // 33750*256 = NN*288 exactly
  fo[i] = 0.f;
  if (i < NN*4) den[i] = 0.f;
}

// ---------- fused edge pass, latency-pipelined ----------
// half-wave = 1 edge, lane c = channel. 16 edges/wave; indices+geometry hoisted to
// wave start (lane l<16 owns edge l, broadcast by shfl); ef/f_in/T gathers
// prefetched 1 iteration ahead. Segmented accumulation flushed by atomicAdd.
template<int FIRST>
__global__ __launch_bounds__(256,2) void k_fused(
    const float* __restrict__ pos, const float* __restrict__ ef,
    const int* __restrict__ src, const int* __restrict__ dst,
    const int* __restrict__ perm,
    const float* __restrict__ f_in, const float* __restrict__ Tq,
    const float* __restrict__ Wr1g, const float* __restrict__ br1g,
    const float* __restrict__ Wr2g,
    float* __restrict__ aggG, float* __restrict__ den)
{
  // W2 packed for ds_read_b128: A=[ci][c][4]={w0,w3,w5,0} (FIRST) or {w0..w3};
  // B=[ci][c][4]={w4,w5,w6,0} (!FIRST). Contiguous 16B/lane -> conflict-free.
  __shared__ float W2A[4096];
  __shared__ float W2B[FIRST ? 4 : 4096];
  int tid = threadIdx.x;
  if (FIRST){
    for (int t=tid;t<4096;t+=256){
      int ci=t>>7, r=t&127, c0=r>>2, j=r&3;
      int k = (j==0)?0:((j==1)?3:((j==2)?5:-1));
      W2A[t] = (k>=0)? Wr2g[ci*224 + k*32 + c0] : 0.f;
    }
  } else {
    for (int t=tid;t<4096;t+=256){
      int ci=t>>7, r=t&127, c0=r>>2, j=r&3;
      W2A[t] = Wr2g[ci*224 + j*32 + c0];
      int k = j+4;
      W2B[t] = (k<7)? Wr2g[ci*224 + k*32 + c0] : 0.f;
    }
  }
  __syncthreads();

  int lane = tid & 63;
  int wv   = tid >> 6;
  int c    = lane & 31;
  int half = lane >> 5;
  int hh   = c >> 3;
  int base = blockIdx.x*64 + wv*16;      // 7500*64 = 480000 exact
  int ll   = lane & 15;

  // W1 column in registers (zero DS in h-loop weight side)
  float w1r[33];
  #pragma unroll
  for (int j=0;j<33;j++) w1r[j] = Wr1g[j*32 + c];
  float b1 = br1g[c];

  // ---- hoist: lane ll owns edge (base+ll): indices + geometry ----
  int pL = base + ll;
  int eL = perm[pL];
  int sL = src[eL];
  int dL = dst[eL];
  float pdx = pos[dL*3+0]-pos[sL*3+0];
  float pdy = pos[dL*3+1]-pos[sL*3+1];
  float pdz = pos[dL*3+2]-pos[sL*3+2];
  float rrL = sqrtf(pdx*pdx+pdy*pdy+pdz*pdz+1e-8f);
  float ivL = 1.f/rrL;
  float y1xL = pdx*ivL, y1yL = pdy*ivL, y1zL = pdz*ivL;

  // ---- prologue: load iteration-0 data ----
  int idx0 = half;
  int sC = __shfl(sL, idx0, 32);
  int dC = __shfl(dL, idx0, 32);
  int eC = __shfl(eL, idx0, 32);
  float rrC  = __shfl(rrL, idx0, 32);
  float y1xC = __shfl(y1xL, idx0, 32);
  float y1yC = __shfl(y1yL, idx0, 32);
  float y1zC = __shfl(y1zL, idx0, 32);
  float rvC = ef[(size_t)eC*32 + c];
  const float* fsC = f_in + (size_t)sC*288;
  float f0C = fsC[c];
  float f1aC=0.f,f1bC=0.f,f1cC=0.f,f2aC=0.f,f2bC=0.f,f2cC=0.f,f2dC=0.f,f2eC=0.f;
  if (!FIRST){
    f1aC=fsC[32+c]; f1bC=fsC[64+c]; f1cC=fsC[96+c];
    f2aC=fsC[128+c]; f2bC=fsC[160+c]; f2cC=fsC[192+c]; f2dC=fsC[224+c]; f2eC=fsC[256+c];
  }
  const float* TC = Tq + (size_t)dC*128;
  float T0C=TC[c], T1C=TC[32+c], T2C=TC[64+c], T3C=TC[96+c];

  float A[9];
  #pragma unroll
  for (int j=0;j<9;j++) A[j]=0.f;
  float denA = 0.f;
  int curd = -1;

  #pragma unroll 1
  for (int it=0; it<8; ++it){
    // ---- prefetch next edge pair (hidden under compute below) ----
    int sN=0,dN=0;
    float rrN=0.f,y1xN=0.f,y1yN=0.f,y1zN=0.f,rvN=0.f;
    float f0N=0.f,f1aN=0.f,f1bN=0.f,f1cN=0.f,f2aN=0.f,f2bN=0.f,f2cN=0.f,f2dN=0.f,f2eN=0.f;
    float T0N=0.f,T1N=0.f,T2N=0.f,T3N=0.f;
    if (it < 7){
      int idn = (it+1)*2 + half;
      int eN = __shfl(eL, idn, 32);
      sN = __shfl(sL, idn, 32);
      dN = __shfl(dL, idn, 32);
      rrN  = __shfl(rrL, idn, 32);
      y1xN = __shfl(y1xL, idn, 32);
      y1yN = __shfl(y1yL, idn, 32);
      y1zN = __shfl(y1zL, idn, 32);
      rvN = ef[(size_t)eN*32 + c];
      const float* fsN = f_in + (size_t)sN*288;
      f0N = fsN[c];
      if (!FIRST){
        f1aN=fsN[32+c]; f1bN=fsN[64+c]; f1cN=fsN[96+c];
        f2aN=fsN[128+c]; f2bN=fsN[160+c]; f2cN=fsN[192+c]; f2dN=fsN[224+c]; f2eN=fsN[256+c];
      }
      const float* TN = Tq + (size_t)dN*128;
      T0N=TN[c]; T1N=TN[32+c]; T2N=TN[64+c]; T3N=TN[96+c];
    }

    // ---- compute current edge ----
    float y2a=y1xC*y1yC, y2b=y1yC*y1zC, y2c=3.f*y1zC*y1zC-1.f, y2d=y1xC*y1zC, y2e=y1xC*y1xC-y1yC*y1yC;

    // h = relu([r, ef] @ W1 + b1)  (4-way split chain)
    float h0 = fmaf(rrC, w1r[0], b1), h1=0.f, h2=0.f, h3=0.f;
    #pragma unroll
    for (int jb=0;jb<8;jb++){
      h0 = fmaf(__shfl(rvC, jb*4+0, 32), w1r[1+jb*4+0], h0);
      h1 = fmaf(__shfl(rvC, jb*4+1, 32), w1r[1+jb*4+1], h1);
      h2 = fmaf(__shfl(rvC, jb*4+2, 32), w1r[1+jb*4+2], h2);
      h3 = fmaf(__shfl(rvC, jb*4+3, 32), w1r[1+jb*4+3], h3);
    }
    float h = fmaxf((h0+h1)+(h2+h3), 0.f);

    // w = h @ W2  (float4 LDS reads, conflict-free)
    float w0=0.f,w1=0.f,w2=0.f,w3=0.f,w4=0.f,w5=0.f,w6=0.f;
    #pragma unroll
    for (int ci=0;ci<32;ci++){
      float hb = __shfl(h, ci, 32);
      float4 qa = *(const float4*)&W2A[ci*128 + c*4];
      if (FIRST){
        w0 = fmaf(hb, qa.x, w0);
        w3 = fmaf(hb, qa.y, w3);
        w5 = fmaf(hb, qa.z, w5);
      } else {
        float4 qb = *(const float4*)&W2B[ci*128 + c*4];
        w0 = fmaf(hb, qa.x, w0);
        w1 = fmaf(hb, qa.y, w1);
        w2 = fmaf(hb, qa.z, w2);
        w3 = fmaf(hb, qa.w, w3);
        w4 = fmaf(hb, qb.x, w4);
        w5 = fmaf(hb, qb.y, w5);
        w6 = fmaf(hb, qb.z, w6);
      }
    }

    float m0v = w0*f0C;
    if (!FIRST){
      m0v += w1*(f1aC*y1xC+f1bC*y1yC+f1cC*y1zC)
           + w2*(f2aC*y2a+f2bC*y2b+f2cC*y2c+f2dC*y2d+f2eC*y2e);
    }

    // logits via precomputed T: per-lane products + 32-lane butterfly
    float p0 = m0v*T0C, p1 = m0v*T1C, p2 = m0v*T2C, p3 = m0v*T3C;
    #pragma unroll
    for (int mk=1;mk<32;mk<<=1){
      p0 += __shfl_xor(p0,mk,32);
      p1 += __shfl_xor(p1,mk,32);
      p2 += __shfl_xor(p2,mk,32);
      p3 += __shfl_xor(p3,mk,32);
    }
    float Sh = (hh==0)?p0:((hh==1)?p1:((hh==2)?p2:p3));
    float el = __expf(Sh * 0.35355339059327373f);   // 1/sqrt(8); logits O(1), no overflow

    if (dC != curd){
      if (curd >= 0){
        #pragma unroll
        for (int j=0;j<9;j++) atomicAdd(&aggG[(size_t)curd*288 + j*32 + c], A[j]);
        if ((c&7)==0) atomicAdd(&den[(size_t)curd*4 + hh], denA);
      }
      #pragma unroll
      for (int j=0;j<9;j++) A[j]=0.f;
      denA = 0.f;
      curd = dC;
    }
    denA += el;
    A[0] = fmaf(el, m0v, A[0]);
    A[1] = fmaf(el, w3*f0C*y1xC + w4*f1aC, A[1]);
    A[2] = fmaf(el, w3*f0C*y1yC + w4*f1bC, A[2]);
    A[3] = fmaf(el, w3*f0C*y1zC + w4*f1cC, A[3]);
    A[4] = fmaf(el, w5*f0C*y2a + w6*f2aC, A[4]);
    A[5] = fmaf(el, w5*f0C*y2b + w6*f2bC, A[5]);
    A[6] = fmaf(el, w5*f0C*y2c + w6*f2cC, A[6]);
    A[7] = fmaf(el, w5*f0C*y2d + w6*f2dC, A[7]);
    A[8] = fmaf(el, w5*f0C*y2e + w6*f2eC, A[8]);

    // ---- rotate pipeline regs ----
    sC=sN; dC=dN; rrC=rrN; y1xC=y1xN; y1yC=y1yN; y1zC=y1zN; rvC=rvN;
    f0C=f0N; f1aC=f1aN; f1bC=f1bN; f1cC=f1cN;
    f2aC=f2aN; f2bC=f2bN; f2cC=f2cN; f2dC=f2dN; f2eC=f2eN;
    T0C=T0N; T1C=T1N; T2C=T2N; T3C=T3N;
  }
  if (curd >= 0){
    #pragma unroll
    for (int j=0;j<9;j++) atomicAdd(&aggG[(size_t)curd*288 + j*32 + c], A[j]);
    if ((c&7)==0) atomicAdd(&den[(size_t)curd*4 + hh], denA);
  }
}

// ---------- node update: f_out = [(agg0/den)@Ws0 + f0@Wsk, (agg1/den)@Ws1, (agg2/den)@Ws2] ----------
__global__ __launch_bounds__(256) void k_update(
    const float* __restrict__ aggG, const float* __restrict__ f_in,
    const float* __restrict__ den,
    const float* __restrict__ Ws0, const float* __restrict__ Ws1,
    const float* __restrict__ Ws2, const float* __restrict__ Wsk,
    float* __restrict__ f_out)
{
  __shared__ float wL[4096];
  __shared__ float agL[8][297];
  __shared__ float f0L[8][33];
  __shared__ float dL[8][4];
  int tid = threadIdx.x;
  int nb = blockIdx.x*8;
  for (int i=tid;i<1024;i+=256){
    wL[i]=Ws0[i]; wL[1024+i]=Ws1[i]; wL[2048+i]=Ws2[i]; wL[3072+i]=Wsk[i];
  }
  if (tid < 32){
    int nl = tid>>2, hd = tid&3;
    dL[nl][hd] = 1.f/(den[(size_t)(nb+nl)*4 + hd] + 1e-30f);
  }
  { int nl=tid>>5, cc=tid&31; f0L[nl][cc] = f_in[(size_t)(nb+nl)*288 + cc]; }
  __syncthreads();
  for (int i=tid;i<2304;i+=256){
    int nl=i/288, F=i-nl*288, r=F>>5, cc=F&31;
    agL[nl][r*33+cc] = aggG[(size_t)(nb+nl)*288 + F] * dL[nl][cc>>3];
  }
  __syncthreads();
  int nl = tid>>5, o = tid&31;
  size_t obase = (size_t)(nb+nl)*288;
  #pragma unroll 1
  for (int r=0;r<9;r++){
    const float* W = (r==0)? wL : ((r<4)? wL+1024 : wL+2048);
    float acc=0.f;
    #pragma unroll
    for (int cc=0;cc<32;cc++) acc = fmaf(agL[nl][r*33+cc], W[cc*32+o], acc);
    if (r==0){
      #pragma unroll
      for (int cc=0;cc<32;cc++) acc = fmaf(f0L[nl][cc], wL[3072 + cc*32+o], acc);
    }
    f_out[obase + r*32 + o] = acc;
  }
}

// ---------- output head (f32 out) ----------
__global__ __launch_bounds__(256) void k_out(
    const float* __restrict__ f_in, const float* __restrict__ Wout,
    const float* __restrict__ Wc, float* __restrict__ out)
{
  __shared__ float sh[8][33];
  int tid = threadIdx.x;
  int nl = tid>>5, c = tid&31;
  int n = blockIdx.x*8 + nl;
  const float* f0 = f_in + (size_t)n*288;
  float acc=0.f;
  #pragma unroll
  for (int ci=0;ci<32;ci++) acc = fmaf(f0[ci], Wout[ci*32+c], acc);
  out[(size_t)n*32 + c] = acc;
  sh[nl][c] = acc;
  __syncthreads();
  if (tid < 120){
    int nl2 = tid/15, j = tid%15;
    int n2 = blockIdx.x*8 + nl2;
    float a = 0.f;
    #pragma unroll
    for (int ci=0;ci<32;ci++) a = fmaf(sh[nl2][ci], Wc[ci*15+j], a);
    out[(size_t)NN*32 + (size_t)n2*15 + j] = a;
  }
}

extern "C" void kernel_launch(void* const* d_in, const int* in_sizes, int n_in,
                              void* d_out, int out_size, void* d_ws, size_t ws_size,
                              hipStream_t stream)
{
  (void)in_sizes; (void)n_in;
  const float* pos       = (const float*)d_in[0];
  const float* node_l0   = (const float*)d_in[1];
  const float* edge_feat = (const float*)d_in[2];
  const int* esrc = (const int*)d_in[3];
  const int* edst = (const int*)d_in[4];
  const float* Wr1  = (const float*)d_in[5];
  const float* br1  = (const float*)d_in[6];
  const float* Wr2  = (const float*)d_in[7];
  const float* Wq   = (const float*)d_in[8];
  const float* Wk   = (const float*)d_in[9];
  const float* Ws0  = (const float*)d_in[10];
  const float* Ws1  = (const float*)d_in[11];
  const float* Ws2  = (const float*)d_in[12];
  const float* Wsk  = (const float*)d_in[13];
  const float* Wout = (const float*)d_in[14];
  const float* Wc   = (const float*)d_in[15];

  char* ws = (char*)d_ws;
  size_t off = 0;
  auto take = [&](size_t bytes)->char*{
    char* p = ws + off;
    off += (bytes + 255) & ~(size_t)255;
    return p;
  };
  float* fA      = (float*)take((size_t)NN*288*4);   // 34.56 MB
  float* fB      = (float*)take((size_t)NN*288*4);   // 34.56 MB
  float* Tq      = (float*)take((size_t)NN*128*4);   // 15.36 MB
  int*   hist    = (int*)  take((size_t)NN*4);
  int*   offs    = (int*)  take((size_t)(NN+1)*4);
  int*   cursor  = (int*)  take((size_t)NN*4);
  int*   perm    = (int*)  take((size_t)EE*4);       //  1.92 MB
  float* den     = (float*)take((size_t)NN*4*4);     //  0.48 MB
  size_t need = off;                                  // ~88 MB (R6 proved >=91 OK)

  if (ws_size < need){
    k_zero<<<(out_size+255)/256,256,0,stream>>>((float*)d_out, out_size);
    return;
  }

  k_init<<<33750,256,0,stream>>>(node_l0, fA, hist);
  k_hist<<<1875,256,0,stream>>>(edst, hist);
  k_scan<<<1,1024,0,stream>>>(hist, offs, cursor, NN);
  k_scatter<<<1875,256,0,stream>>>(edst, cursor, perm);

  float* fi = fA; float* fo = fB;
  for (int l=0; l<2; ++l){
    k_zeroagg<<<33750,256,0,stream>>>(fo, den);
    k_qt<<<3750,256,0,stream>>>(fi, Wq + l*1024, Wk + l*1024, Tq);
    if (l==0){
      k_fused<1><<<7500,256,0,stream>>>(pos, edge_feat, esrc, edst, perm,
          fi, Tq, Wr1 + l*1056, br1 + l*32, Wr2 + l*7168,
          fo, den);
    } else {
      k_fused<0><<<7500,256,0,stream>>>(pos, edge_feat, esrc, edst, perm,
          fi, Tq, Wr1 + l*1056, br1 + l*32, Wr2 + l*7168,
          fo, den);
    }
    k_update<<<3750,256,0,stream>>>(fo, fi, den,
        Ws0 + l*1024, Ws1 + l*1024, Ws2 + l*1024, Wsk + l*1024, fo);
    float* tmp = fi; fi = fo; fo = tmp;
  }
  k_out<<<3750,256,0,stream>>>(fi, Wout, Wc, (float*)d_out);
}

// Round 5
// 1592.911 us; speedup vs baseline: 2.7812x; 2.7812x over previous
//
#include <hip/hip_runtime.h>

#define NN 30000
#define EE 480000

// ---------- zero-fill fallback (ws too small diagnostic) ----------
__global__ __launch_bounds__(256) void k_zero(float* __restrict__ out, int n){
  int i = blockIdx.x*256 + threadIdx.x;
  if (i < n) out[i] = 0.f;
}

// ---------- node feature init: fA[N][288] (row0=node_l0, rest 0), hist=0 ----------
__global__ __launch_bounds__(256) void k_init(
    const float* __restrict__ nl0, float* __restrict__ fA, int* __restrict__ hist)
{
  int i = blockIdx.x*256 + threadIdx.x;   // exactly N*288
  int n = i/288; int r2 = i - n*288;
  fA[i] = (r2 < 32) ? nl0[(size_t)n*32 + r2] : 0.f;
  if (i < NN) hist[i] = 0;
}

__global__ __launch_bounds__(256) void k_hist(const int* __restrict__ dst, int* __restrict__ hist){
  int e = blockIdx.x*256 + threadIdx.x;
  if (e < EE) atomicAdd(&hist[dst[e]], 1);
}

// single-block exclusive scan over hist[NN] -> offs, cursor
__global__ void k_scan(const int* __restrict__ hist, int* __restrict__ offs,
                       int* __restrict__ cursor, int n)
{
  __shared__ int sm[1024];
  __shared__ int carry;
  int tid = threadIdx.x;
  if (tid==0) carry = 0;
  __syncthreads();
  for (int base=0; base<n; base+=1024){
    int i = base + tid;
    int v = (i<n)? hist[i] : 0;
    sm[tid] = v; __syncthreads();
    for (int o=1;o<1024;o<<=1){
      int tv = (tid>=o)? sm[tid-o] : 0;
      __syncthreads();
      sm[tid] += tv;
      __syncthreads();
    }
    int cy = carry;
    int excl = sm[tid] - v;
    if (i<n){ offs[i] = cy+excl; cursor[i] = cy+excl; }
    __syncthreads();
    if (tid==1023) carry = cy + sm[1023];
    __syncthreads();
  }
  if (tid==0) offs[n] = carry;
}

__global__ __launch_bounds__(256) void k_scatter(const int* __restrict__ dst,
    int* __restrict__ cursor, int* __restrict__ perm)
{
  int e = blockIdx.x*256 + threadIdx.x;
  if (e >= EE) return;
  int d = dst[e];
  int p = atomicAdd(&cursor[d], 1);
  perm[p] = e;
}

// ---------- per-node q projection folded into T: T[n][h][ci] = sum_o Wk[ci][h*8+o]*q[n][h*8+o] ----------
// logits_h(edge) = sum_ci m0[ci]*T[d][h][ci]  (eliminates per-edge k-projection)
__global__ __launch_bounds__(256) void k_qt(
    const float* __restrict__ f_in, const float* __restrict__ Wqf,
    const float* __restrict__ Wkf, float* __restrict__ Tq)
{
  __shared__ float WqL[1024];
  __shared__ float WkL[1056];           // [c][33] padded: bank-conflict-free row reads
  int tid = threadIdx.x;
  for (int i=tid;i<1024;i+=256) WqL[i]=Wqf[i];
  for (int i=tid;i<1056;i+=256){ int r=i/33, o=i-r*33; if (o<32) WkL[i]=Wkf[r*32+o]; }
  __syncthreads();
  int n = blockIdx.x*8 + (tid>>5), c = tid&31;
  const float* f0 = f_in + (size_t)n*288;
  float q=0.f;
  #pragma unroll
  for (int ci=0;ci<32;ci++) q = fmaf(f0[ci], WqL[ci*32+c], q);
  float t0=0.f,t1=0.f,t2=0.f,t3=0.f;
  #pragma unroll
  for (int j=0;j<32;j++){
    float qb = __shfl(q, j, 32);
    float wv = WkL[c*33 + j];
    if (j<8)       t0 = fmaf(wv, qb, t0);
    else if (j<16) t1 = fmaf(wv, qb, t1);
    else if (j<24) t2 = fmaf(wv, qb, t2);
    else           t3 = fmaf(wv, qb, t3);
  }
  float* T = Tq + (size_t)n*128;
  T[c]=t0; T[32+c]=t1; T[64+c]=t2; T[96+c]=t3;
}

// ---------- zero agg buffer + den ----------
__global__ __launch_bounds__(256) void k_zeroagg(float* __restrict__ fo, float* __restrict__ den){
  int i = blockIdx.x*256 + threadIdx.x;   // 33750*256 = NN*288 exactly
  fo[i] = 0.f;
  if (i < NN*4) den[i] = 0.f;
}

// ---------- fused edge pass, spill-safe latency pipeline ----------
// half-wave = 1 edge, lane c = channel. 16 edges/wave; lane ll (=lane&15) owns
// edge base+ll's indices+geometry (lanes 16..31 duplicate 0..15, making the
// it=7 prefetch index 16/17 a VALID dummy -> branchless pipeline, no dual-path
// register liveness). Only per-lane gathers (ef:1, f:9, T:4 regs) are
// double-buffered; everything else re-broadcast via shfl at use time.
template<int FIRST>
__global__ __launch_bounds__(256) void k_fused(
    const float* __restrict__ pos, const float* __restrict__ ef,
    const int* __restrict__ src, const int* __restrict__ dst,
    const int* __restrict__ perm,
    const float* __restrict__ f_in, const float* __restrict__ Tq,
    const float* __restrict__ Wr1g, const float* __restrict__ br1g,
    const float* __restrict__ Wr2g,
    float* __restrict__ aggG, float* __restrict__ den)
{
  // W2 packed for ds_read_b128: A=[ci][c][4]={w0,w3,w5,0} (FIRST) or {w0..w3};
  // B=[ci][c][4]={w4,w5,w6,0} (!FIRST). Contiguous 16B/lane -> conflict-free.
  __shared__ float W2A[4096];
  __shared__ float W2B[FIRST ? 4 : 4096];
  int tid = threadIdx.x;
  if (FIRST){
    for (int t=tid;t<4096;t+=256){
      int ci=t>>7, r=t&127, c0=r>>2, j=r&3;
      int k = (j==0)?0:((j==1)?3:((j==2)?5:-1));
      W2A[t] = (k>=0)? Wr2g[ci*224 + k*32 + c0] : 0.f;
    }
  } else {
    for (int t=tid;t<4096;t+=256){
      int ci=t>>7, r=t&127, c0=r>>2, j=r&3;
      W2A[t] = Wr2g[ci*224 + j*32 + c0];
      int k = j+4;
      W2B[t] = (k<7)? Wr2g[ci*224 + k*32 + c0] : 0.f;
    }
  }
  __syncthreads();

  int lane = tid & 63;
  int wv   = tid >> 6;
  int c    = lane & 31;
  int half = lane >> 5;
  int hh   = c >> 3;
  int base = blockIdx.x*64 + wv*16;      // 7500*64 = 480000 exact
  int ll   = lane & 15;

  // W1 column in registers (zero DS on weight side of h-loop)
  float w1r[33];
  #pragma unroll
  for (int j=0;j<33;j++) w1r[j] = Wr1g[j*32 + c];
  float b1 = br1g[c];

  // ---- lane-owned edge (ll): indices + geometry; lanes 16..31 duplicate 0..15 ----
  int eL = perm[base + ll];
  int sL = src[eL];
  int dL = dst[eL];
  float pdx = pos[dL*3+0]-pos[sL*3+0];
  float pdy = pos[dL*3+1]-pos[sL*3+1];
  float pdz = pos[dL*3+2]-pos[sL*3+2];
  float rrL = sqrtf(pdx*pdx+pdy*pdy+pdz*pdz+1e-8f);
  float ivL = 1.f/rrL;
  float y1xL = pdx*ivL, y1yL = pdy*ivL, y1zL = pdz*ivL;

  // ---- prologue: gathers for pair 0 ----
  int eP = __shfl(eL, half, 32);
  int sP = __shfl(sL, half, 32);
  int dP = __shfl(dL, half, 32);
  float rvP = ef[(size_t)eP*32 + c];
  const float* fsP = f_in + (size_t)sP*288;
  float f0P = fsP[c];
  float f1aP=0.f,f1bP=0.f,f1cP=0.f,f2aP=0.f,f2bP=0.f,f2cP=0.f,f2dP=0.f,f2eP=0.f;
  if (!FIRST){
    f1aP=fsP[32+c]; f1bP=fsP[64+c]; f1cP=fsP[96+c];
    f2aP=fsP[128+c]; f2bP=fsP[160+c]; f2cP=fsP[192+c]; f2dP=fsP[224+c]; f2eP=fsP[256+c];
  }
  const float* TP = Tq + (size_t)dP*128;
  float T0P=TP[c], T1P=TP[32+c], T2P=TP[64+c], T3P=TP[96+c];

  float A[9];
  #pragma unroll
  for (int j=0;j<9;j++) A[j]=0.f;
  float denA = 0.f;
  int curd = -1;

  #pragma unroll 1
  for (int it=0; it<8; ++it){
    // ---- consume pipeline regs into current ----
    float rvC=rvP;
    float f0C=f0P, f1aC=f1aP, f1bC=f1bP, f1cC=f1cP;
    float f2aC=f2aP, f2bC=f2bP, f2cC=f2cP, f2dC=f2dP, f2eC=f2eP;
    float T0C=T0P, T1C=T1P, T2C=T2P, T3C=T3P;

    // ---- branchless prefetch of pair it+1 (it=7 -> lanes 16/17, valid dummy) ----
    {
      int idn = (it+1)*2 + half;
      int eN = __shfl(eL, idn, 32);
      int sN = __shfl(sL, idn, 32);
      int dN = __shfl(dL, idn, 32);
      rvP = ef[(size_t)eN*32 + c];
      const float* fsN = f_in + (size_t)sN*288;
      f0P = fsN[c];
      if (!FIRST){
        f1aP=fsN[32+c]; f1bP=fsN[64+c]; f1cP=fsN[96+c];
        f2aP=fsN[128+c]; f2bP=fsN[160+c]; f2cP=fsN[192+c]; f2dP=fsN[224+c]; f2eP=fsN[256+c];
      }
      const float* TN = Tq + (size_t)dN*128;
      T0P=TN[c]; T1P=TN[32+c]; T2P=TN[64+c]; T3P=TN[96+c];
    }

    // ---- broadcast geometry for current pair ----
    int idc = it*2 + half;
    int dC     = __shfl(dL, idc, 32);
    float rrC  = __shfl(rrL, idc, 32);
    float y1xC = __shfl(y1xL, idc, 32);
    float y1yC = __shfl(y1yL, idc, 32);
    float y1zC = __shfl(y1zL, idc, 32);
    float y2a=y1xC*y1yC, y2b=y1yC*y1zC, y2c=3.f*y1zC*y1zC-1.f, y2d=y1xC*y1zC, y2e=y1xC*y1xC-y1yC*y1yC;

    // h = relu([r, ef] @ W1 + b1)  (4-way split chains)
    float h0 = fmaf(rrC, w1r[0], b1), h1=0.f, h2=0.f, h3=0.f;
    #pragma unroll
    for (int jb=0;jb<8;jb++){
      h0 = fmaf(__shfl(rvC, jb*4+0, 32), w1r[1+jb*4+0], h0);
      h1 = fmaf(__shfl(rvC, jb*4+1, 32), w1r[1+jb*4+1], h1);
      h2 = fmaf(__shfl(rvC, jb*4+2, 32), w1r[1+jb*4+2], h2);
      h3 = fmaf(__shfl(rvC, jb*4+3, 32), w1r[1+jb*4+3], h3);
    }
    float h = fmaxf((h0+h1)+(h2+h3), 0.f);

    // w = h @ W2  (float4 LDS reads, conflict-free)
    float w0=0.f,w1=0.f,w2=0.f,w3=0.f,w4=0.f,w5=0.f,w6=0.f;
    #pragma unroll
    for (int ci=0;ci<32;ci++){
      float hb = __shfl(h, ci, 32);
      float4 qa = *(const float4*)&W2A[ci*128 + c*4];
      if (FIRST){
        w0 = fmaf(hb, qa.x, w0);
        w3 = fmaf(hb, qa.y, w3);
        w5 = fmaf(hb, qa.z, w5);
      } else {
        float4 qb = *(const float4*)&W2B[ci*128 + c*4];
        w0 = fmaf(hb, qa.x, w0);
        w1 = fmaf(hb, qa.y, w1);
        w2 = fmaf(hb, qa.z, w2);
        w3 = fmaf(hb, qa.w, w3);
        w4 = fmaf(hb, qb.x, w4);
        w5 = fmaf(hb, qb.y, w5);
        w6 = fmaf(hb, qb.z, w6);
      }
    }

    float m0v = w0*f0C;
    if (!FIRST){
      m0v += w1*(f1aC*y1xC+f1bC*y1yC+f1cC*y1zC)
           + w2*(f2aC*y2a+f2bC*y2b+f2cC*y2c+f2dC*y2d+f2eC*y2e);
    }

    // logits via precomputed T: per-lane products + 32-lane butterfly
    float p0 = m0v*T0C, p1 = m0v*T1C, p2 = m0v*T2C, p3 = m0v*T3C;
    #pragma unroll
    for (int mk=1;mk<32;mk<<=1){
      p0 += __shfl_xor(p0,mk,32);
      p1 += __shfl_xor(p1,mk,32);
      p2 += __shfl_xor(p2,mk,32);
      p3 += __shfl_xor(p3,mk,32);
    }
    float Sh = (hh==0)?p0:((hh==1)?p1:((hh==2)?p2:p3));
    float el = __expf(Sh * 0.35355339059327373f);   // 1/sqrt(8); logits O(1), no overflow

    if (dC != curd){
      if (curd >= 0){
        #pragma unroll
        for (int j=0;j<9;j++) atomicAdd(&aggG[(size_t)curd*288 + j*32 + c], A[j]);
        if ((c&7)==0) atomicAdd(&den[(size_t)curd*4 + hh], denA);
      }
      #pragma unroll
      for (int j=0;j<9;j++) A[j]=0.f;
      denA = 0.f;
      curd = dC;
    }
    denA += el;
    A[0] = fmaf(el, m0v, A[0]);
    A[1] = fmaf(el, w3*f0C*y1xC + w4*f1aC, A[1]);
    A[2] = fmaf(el, w3*f0C*y1yC + w4*f1bC, A[2]);
    A[3] = fmaf(el, w3*f0C*y1zC + w4*f1cC, A[3]);
    A[4] = fmaf(el, w5*f0C*y2a + w6*f2aC, A[4]);
    A[5] = fmaf(el, w5*f0C*y2b + w6*f2bC, A[5]);
    A[6] = fmaf(el, w5*f0C*y2c + w6*f2cC, A[6]);
    A[7] = fmaf(el, w5*f0C*y2d + w6*f2dC, A[7]);
    A[8] = fmaf(el, w5*f0C*y2e + w6*f2eC, A[8]);
  }
  if (curd >= 0){
    #pragma unroll
    for (int j=0;j<9;j++) atomicAdd(&aggG[(size_t)curd*288 + j*32 + c], A[j]);
    if ((c&7)==0) atomicAdd(&den[(size_t)curd*4 + hh], denA);
  }
}

// ---------- node update: f_out = [(agg0/den)@Ws0 + f0@Wsk, (agg1/den)@Ws1, (agg2/den)@Ws2] ----------
__global__ __launch_bounds__(256) void k_update(
    const float* __restrict__ aggG, const float* __restrict__ f_in,
    const float* __restrict__ den,
    const float* __restrict__ Ws0, const float* __restrict__ Ws1,
    const float* __restrict__ Ws2, const float* __restrict__ Wsk,
    float* __restrict__ f_out)
{
  __shared__ float wL[4096];
  __shared__ float agL[8][297];
  __shared__ float f0L[8][33];
  __shared__ float dL[8][4];
  int tid = threadIdx.x;
  int nb = blockIdx.x*8;
  for (int i=tid;i<1024;i+=256){
    wL[i]=Ws0[i]; wL[1024+i]=Ws1[i]; wL[2048+i]=Ws2[i]; wL[3072+i]=Wsk[i];
  }
  if (tid < 32){
    int nl = tid>>2, hd = tid&3;
    dL[nl][hd] = 1.f/(den[(size_t)(nb+nl)*4 + hd] + 1e-30f);
  }
  { int nl=tid>>5, cc=tid&31; f0L[nl][cc] = f_in[(size_t)(nb+nl)*288 + cc]; }
  __syncthreads();
  for (int i=tid;i<2304;i+=256){
    int nl=i/288, F=i-nl*288, r=F>>5, cc=F&31;
    agL[nl][r*33+cc] = aggG[(size_t)(nb+nl)*288 + F] * dL[nl][cc>>3];
  }
  __syncthreads();
  int nl = tid>>5, o = tid&31;
  size_t obase = (size_t)(nb+nl)*288;
  #pragma unroll 1
  for (int r=0;r<9;r++){
    const float* W = (r==0)? wL : ((r<4)? wL+1024 : wL+2048);
    float acc=0.f;
    #pragma unroll
    for (int cc=0;cc<32;cc++) acc = fmaf(agL[nl][r*33+cc], W[cc*32+o], acc);
    if (r==0){
      #pragma unroll
      for (int cc=0;cc<32;cc++) acc = fmaf(f0L[nl][cc], wL[3072 + cc*32+o], acc);
    }
    f_out[obase + r*32 + o] = acc;
  }
}

// ---------- output head (f32 out) ----------
__global__ __launch_bounds__(256) void k_out(
    const float* __restrict__ f_in, const float* __restrict__ Wout,
    const float* __restrict__ Wc, float* __restrict__ out)
{
  __shared__ float sh[8][33];
  int tid = threadIdx.x;
  int nl = tid>>5, c = tid&31;
  int n = blockIdx.x*8 + nl;
  const float* f0 = f_in + (size_t)n*288;
  float acc=0.f;
  #pragma unroll
  for (int ci=0;ci<32;ci++) acc = fmaf(f0[ci], Wout[ci*32+c], acc);
  out[(size_t)n*32 + c] = acc;
  sh[nl][c] = acc;
  __syncthreads();
  if (tid < 120){
    int nl2 = tid/15, j = tid%15;
    int n2 = blockIdx.x*8 + nl2;
    float a = 0.f;
    #pragma unroll
    for (int ci=0;ci<32;ci++) a = fmaf(sh[nl2][ci], Wc[ci*15+j], a);
    out[(size_t)NN*32 + (size_t)n2*15 + j] = a;
  }
}

extern "C" void kernel_launch(void* const* d_in, const int* in_sizes, int n_in,
                              void* d_out, int out_size, void* d_ws, size_t ws_size,
                              hipStream_t stream)
{
  (void)in_sizes; (void)n_in;
  const float* pos       = (const float*)d_in[0];
  const float* node_l0   = (const float*)d_in[1];
  const float* edge_feat = (const float*)d_in[2];
  const int* esrc = (const int*)d_in[3];
  const int* edst = (const int*)d_in[4];
  const float* Wr1  = (const float*)d_in[5];
  const float* br1  = (const float*)d_in[6];
  const float* Wr2  = (const float*)d_in[7];
  const float* Wq   = (const float*)d_in[8];
  const float* Wk   = (const float*)d_in[9];
  const float* Ws0  = (const float*)d_in[10];
  const float* Ws1  = (const float*)d_in[11];
  const float* Ws2  = (const float*)d_in[12];
  const float* Wsk  = (const float*)d_in[13];
  const float* Wout = (const float*)d_in[14];
  const float* Wc   = (const float*)d_in[15];

  char* ws = (char*)d_ws;
  size_t off = 0;
  auto take = [&](size_t bytes)->char*{
    char* p = ws + off;
    off += (bytes + 255) & ~(size_t)255;
    return p;
  };
  float* fA      = (float*)take((size_t)NN*288*4);   // 34.56 MB
  float* fB      = (float*)take((size_t)NN*288*4);   // 34.56 MB
  float* Tq      = (float*)take((size_t)NN*128*4);   // 15.36 MB
  int*   hist    = (int*)  take((size_t)NN*4);
  int*   offs    = (int*)  take((size_t)(NN+1)*4);
  int*   cursor  = (int*)  take((size_t)NN*4);
  int*   perm    = (int*)  take((size_t)EE*4);       //  1.92 MB
  float* den     = (float*)take((size_t)NN*4*4);     //  0.48 MB
  size_t need = off;                                  // ~88 MB

  if (ws_size < need){
    k_zero<<<(out_size+255)/256,256,0,stream>>>((float*)d_out, out_size);
    return;
  }

  k_init<<<33750,256,0,stream>>>(node_l0, fA, hist);
  k_hist<<<1875,256,0,stream>>>(edst, hist);
  k_scan<<<1,1024,0,stream>>>(hist, offs, cursor, NN);
  k_scatter<<<1875,256,0,stream>>>(edst, cursor, perm);

  float* fi = fA; float* fo = fB;
  for (int l=0; l<2; ++l){
    k_zeroagg<<<33750,256,0,stream>>>(fo, den);
    k_qt<<<3750,256,0,stream>>>(fi, Wq + l*1024, Wk + l*1024, Tq);
    if (l==0){
      k_fused<1><<<7500,256,0,stream>>>(pos, edge_feat, esrc, edst, perm,
          fi, Tq, Wr1 + l*1056, br1 + l*32, Wr2 + l*7168,
          fo, den);
    } else {
      k_fused<0><<<7500,256,0,stream>>>(pos, edge_feat, esrc, edst, perm,
          fi, Tq, Wr1 + l*1056, br1 + l*32, Wr2 + l*7168,
          fo, den);
    }
    k_update<<<3750,256,0,stream>>>(fo, fi, den,
        Ws0 + l*1024, Ws1 + l*1024, Ws2 + l*1024, Wsk + l*1024, fo);
    float* tmp = fi; fi = fo; fo = tmp;
  }
  k_out<<<3750,256,0,stream>>>(fi, Wout, Wc, (float*)d_out);
}

// Round 6
// 1331.895 us; speedup vs baseline: 3.3262x; 1.1960x over previous
//
#include <hip/hip_runtime.h>

#define NN 30000
#define EE 480000

// ---------- zero-fill fallback (ws too small diagnostic) ----------
__global__ __launch_bounds__(256) void k_zero(float* __restrict__ out, int n){
  int i = blockIdx.x*256 + threadIdx.x;
  if (i < n) out[i] = 0.f;
}

// ---------- node feature init: fA[N][288] (row0=node_l0, rest 0), hist=0 ----------
__global__ __launch_bounds__(256) void k_init(
    const float* __restrict__ nl0, float* __restrict__ fA, int* __restrict__ hist)
{
  int i = blockIdx.x*256 + threadIdx.x;   // exactly N*288
  int n = i/288; int r2 = i - n*288;
  fA[i] = (r2 < 32) ? nl0[(size_t)n*32 + r2] : 0.f;
  if (i < NN) hist[i] = 0;
}

__global__ __launch_bounds__(256) void k_hist(const int* __restrict__ dst, int* __restrict__ hist){
  int e = blockIdx.x*256 + threadIdx.x;
  if (e < EE) atomicAdd(&hist[dst[e]], 1);
}

// single-block exclusive scan over hist[NN] -> offs, cursor
__global__ void k_scan(const int* __restrict__ hist, int* __restrict__ offs,
                       int* __restrict__ cursor, int n)
{
  __shared__ int sm[1024];
  __shared__ int carry;
  int tid = threadIdx.x;
  if (tid==0) carry = 0;
  __syncthreads();
  for (int base=0; base<n; base+=1024){
    int i = base + tid;
    int v = (i<n)? hist[i] : 0;
    sm[tid] = v; __syncthreads();
    for (int o=1;o<1024;o<<=1){
      int tv = (tid>=o)? sm[tid-o] : 0;
      __syncthreads();
      sm[tid] += tv;
      __syncthreads();
    }
    int cy = carry;
    int excl = sm[tid] - v;
    if (i<n){ offs[i] = cy+excl; cursor[i] = cy+excl; }
    __syncthreads();
    if (tid==1023) carry = cy + sm[1023];
    __syncthreads();
  }
  if (tid==0) offs[n] = carry;
}

__global__ __launch_bounds__(256) void k_scatter(const int* __restrict__ dst,
    int* __restrict__ cursor, int* __restrict__ perm)
{
  int e = blockIdx.x*256 + threadIdx.x;
  if (e >= EE) return;
  int d = dst[e];
  int p = atomicAdd(&cursor[d], 1);
  perm[p] = e;
}

// ---------- per-node q projection folded into T ----------
__global__ __launch_bounds__(256) void k_qt(
    const float* __restrict__ f_in, const float* __restrict__ Wqf,
    const float* __restrict__ Wkf, float* __restrict__ Tq)
{
  __shared__ float WqL[1024];
  __shared__ float WkL[1056];           // [c][33] padded
  int tid = threadIdx.x;
  for (int i=tid;i<1024;i+=256) WqL[i]=Wqf[i];
  for (int i=tid;i<1056;i+=256){ int r=i/33, o=i-r*33; if (o<32) WkL[i]=Wkf[r*32+o]; }
  __syncthreads();
  int n = blockIdx.x*8 + (tid>>5), c = tid&31;
  const float* f0 = f_in + (size_t)n*288;
  float q=0.f;
  #pragma unroll
  for (int ci=0;ci<32;ci++) q = fmaf(f0[ci], WqL[ci*32+c], q);
  float t0=0.f,t1=0.f,t2=0.f,t3=0.f;
  #pragma unroll
  for (int j=0;j<32;j++){
    float qb = __shfl(q, j, 32);
    float wv = WkL[c*33 + j];
    if (j<8)       t0 = fmaf(wv, qb, t0);
    else if (j<16) t1 = fmaf(wv, qb, t1);
    else if (j<24) t2 = fmaf(wv, qb, t2);
    else           t3 = fmaf(wv, qb, t3);
  }
  float* T = Tq + (size_t)n*128;
  T[c]=t0; T[32+c]=t1; T[64+c]=t2; T[96+c]=t3;
}

// ---------- zero agg buffer + den ----------
__global__ __launch_bounds__(256) void k_zeroagg(float* __restrict__ fo, float* __restrict__ den){
  int i = blockIdx.x*256 + threadIdx.x;
  fo[i] = 0.f;
  if (i < NN*4) den[i] = 0.f;
}

// DPP quad_perm xor1 / xor2 (VALU pipe, replaces ds_bpermute butterfly stages)
__device__ __forceinline__ float dppx1(float x){
  return __int_as_float(__builtin_amdgcn_mov_dpp(__float_as_int(x), 0xB1, 0xF, 0xF, true));
}
__device__ __forceinline__ float dppx2(float x){
  return __int_as_float(__builtin_amdgcn_mov_dpp(__float_as_int(x), 0x4E, 0xF, 0xF, true));
}

// ---------- fused edge pass: 4 edges/wave-iteration, LDS-staged broadcasts ----------
// Half-wave (c=lane&31) carries TWO edges (A,B) per iteration so the 64 W2
// ds_read_b128 serve 4 edges (16/edge, was 32/edge). ef-row and h broadcasts go
// through LDS (same-wave write->read, no barrier) as uniform-per-half float4
// reads (8 ops) instead of 32 ds_bpermute. Geometry staged once per wave as
// float4. Prefetch is branchless: lane ll=lane&15 owns edge base+ll; the it=3
// prefetch index (16..19) lands on duplicate lanes -> valid dummy.
template<int FIRST>
__global__ __launch_bounds__(256) void k_fused(
    const float* __restrict__ pos, const float* __restrict__ ef,
    const int* __restrict__ src, const int* __restrict__ dst,
    const int* __restrict__ perm,
    const float* __restrict__ f_in, const float* __restrict__ Tq,
    const float* __restrict__ Wr1g, const float* __restrict__ br1g,
    const float* __restrict__ Wr2g,
    float* __restrict__ aggG, float* __restrict__ den)
{
  __shared__ __align__(16) float W2A[4096];
  __shared__ __align__(16) float W2B[FIRST ? 4 : 4096];
  __shared__ __align__(16) float rvL[4][4][32];
  __shared__ __align__(16) float hL [4][4][32];
  __shared__ float4 geoL[4][16];
  int tid = threadIdx.x;
  if (FIRST){
    for (int t=tid;t<4096;t+=256){
      int ci=t>>7, r=t&127, c0=r>>2, j=r&3;
      int k = (j==0)?0:((j==1)?3:((j==2)?5:-1));
      W2A[t] = (k>=0)? Wr2g[ci*224 + k*32 + c0] : 0.f;
    }
  } else {
    for (int t=tid;t<4096;t+=256){
      int ci=t>>7, r=t&127, c0=r>>2, j=r&3;
      W2A[t] = Wr2g[ci*224 + j*32 + c0];
      int k = j+4;
      W2B[t] = (k<7)? Wr2g[ci*224 + k*32 + c0] : 0.f;
    }
  }
  __syncthreads();

  int lane = tid & 63;
  int wv   = tid >> 6;
  int c    = lane & 31;
  int half = lane >> 5;
  int hh   = c >> 3;
  int base = blockIdx.x*64 + wv*16;      // 7500*64 = 480000 exact
  int ll   = lane & 15;

  // W1 column in registers (zero DS on weight side of h-loop)
  float w1r[33];
  #pragma unroll
  for (int j=0;j<33;j++) w1r[j] = Wr1g[j*32 + c];
  float b1 = br1g[c];

  // ---- lane-owned edge (ll); lanes 16..31 duplicate 0..15 ----
  int eL = perm[base + ll];
  int sL = src[eL];
  int dL = dst[eL];
  {
    float pdx = pos[dL*3+0]-pos[sL*3+0];
    float pdy = pos[dL*3+1]-pos[sL*3+1];
    float pdz = pos[dL*3+2]-pos[sL*3+2];
    float rr = sqrtf(pdx*pdx+pdy*pdy+pdz*pdz+1e-8f);
    float iv = 1.f/rr;
    if (lane < 16) geoL[wv][ll] = make_float4(rr, pdx*iv, pdy*iv, pdz*iv);
  }

  // ---- prologue gathers for iteration 0 (edges 2*half, 2*half+1) ----
  int eA = __shfl(eL, 2*half,   32);
  int eB = __shfl(eL, 2*half+1, 32);
  int sA = __shfl(sL, 2*half,   32);
  int sB = __shfl(sL, 2*half+1, 32);
  int dA = __shfl(dL, 2*half,   32);
  int dB = __shfl(dL, 2*half+1, 32);
  float rvPa = ef[(size_t)eA*32 + c];
  float rvPb = ef[(size_t)eB*32 + c];
  const float* fsA = f_in + (size_t)sA*288;
  const float* fsB = f_in + (size_t)sB*288;
  float fa0 = fsA[c], fb0 = fsB[c];
  float fa1=0.f,fa2=0.f,fa3=0.f,fa4=0.f,fa5=0.f,fa6=0.f,fa7=0.f,fa8=0.f;
  float fb1=0.f,fb2=0.f,fb3=0.f,fb4=0.f,fb5=0.f,fb6=0.f,fb7=0.f,fb8=0.f;
  if (!FIRST){
    fa1=fsA[32+c]; fa2=fsA[64+c]; fa3=fsA[96+c]; fa4=fsA[128+c];
    fa5=fsA[160+c]; fa6=fsA[192+c]; fa7=fsA[224+c]; fa8=fsA[256+c];
    fb1=fsB[32+c]; fb2=fsB[64+c]; fb3=fsB[96+c]; fb4=fsB[128+c];
    fb5=fsB[160+c]; fb6=fsB[192+c]; fb7=fsB[224+c]; fb8=fsB[256+c];
  }
  const float* TAp = Tq + (size_t)dA*128;
  const float* TBp = Tq + (size_t)dB*128;
  float Ta0=TAp[c], Ta1=TAp[32+c], Ta2=TAp[64+c], Ta3=TAp[96+c];
  float Tb0=TBp[c], Tb1=TBp[32+c], Tb2=TBp[64+c], Tb3=TBp[96+c];

  float A[9];
  #pragma unroll
  for (int j=0;j<9;j++) A[j]=0.f;
  float denA = 0.f;
  int curd = -1;

  #pragma unroll 1
  for (int it=0; it<4; ++it){
    // ---- capture current ----
    int dCa = dA, dCb = dB;
    float ca0=fa0,ca1=fa1,ca2=fa2,ca3=fa3,ca4=fa4,ca5=fa5,ca6=fa6,ca7=fa7,ca8=fa8;
    float cb0=fb0,cb1=fb1,cb2=fb2,cb3=fb3,cb4=fb4,cb5=fb5,cb6=fb6,cb7=fb7,cb8=fb8;
    float Sa0=Ta0,Sa1=Ta1,Sa2=Ta2,Sa3=Ta3;
    float Sb0=Tb0,Sb1=Tb1,Sb2=Tb2,Sb3=Tb3;
    // commit staged ef rows (loads issued last iteration -> latency hidden)
    rvL[wv][half*2+0][c] = rvPa;
    rvL[wv][half*2+1][c] = rvPb;

    // ---- branchless prefetch of iteration it+1 (it=3 -> lanes 16..19 dummy) ----
    {
      int ia = (it+1)*4 + 2*half, ib = ia+1;
      eA = __shfl(eL, ia, 32); eB = __shfl(eL, ib, 32);
      sA = __shfl(sL, ia, 32); sB = __shfl(sL, ib, 32);
      dA = __shfl(dL, ia, 32); dB = __shfl(dL, ib, 32);
      rvPa = ef[(size_t)eA*32 + c];
      rvPb = ef[(size_t)eB*32 + c];
      const float* fsA2 = f_in + (size_t)sA*288;
      const float* fsB2 = f_in + (size_t)sB*288;
      fa0 = fsA2[c]; fb0 = fsB2[c];
      if (!FIRST){
        fa1=fsA2[32+c]; fa2=fsA2[64+c]; fa3=fsA2[96+c]; fa4=fsA2[128+c];
        fa5=fsA2[160+c]; fa6=fsA2[192+c]; fa7=fsA2[224+c]; fa8=fsA2[256+c];
        fb1=fsB2[32+c]; fb2=fsB2[64+c]; fb3=fsB2[96+c]; fb4=fsB2[128+c];
        fb5=fsB2[160+c]; fb6=fsB2[192+c]; fb7=fsB2[224+c]; fb8=fsB2[256+c];
      }
      const float* TA2 = Tq + (size_t)dA*128;
      const float* TB2 = Tq + (size_t)dB*128;
      Ta0=TA2[c]; Ta1=TA2[32+c]; Ta2=TA2[64+c]; Ta3=TA2[96+c];
      Tb0=TB2[c]; Tb1=TB2[32+c]; Tb2=TB2[64+c]; Tb3=TB2[96+c];
    }

    // ---- geometry for current edges (uniform-per-half LDS read) ----
    int ea_idx = it*4 + 2*half;
    float4 ga = geoL[wv][ea_idx];
    float4 gb = geoL[wv][ea_idx+1];

    // ---- h for both edges (rv via uniform float4 LDS reads) ----
    float ha0 = fmaf(ga.x, w1r[0], b1), ha1=0.f, ha2=0.f, ha3=0.f;
    float hb0 = fmaf(gb.x, w1r[0], b1), hb1=0.f, hb2=0.f, hb3=0.f;
    #pragma unroll
    for (int jb=0;jb<8;jb++){
      float4 ra = *(const float4*)&rvL[wv][half*2+0][jb*4];
      float4 rb = *(const float4*)&rvL[wv][half*2+1][jb*4];
      ha0 = fmaf(ra.x, w1r[1+jb*4+0], ha0);
      ha1 = fmaf(ra.y, w1r[1+jb*4+1], ha1);
      ha2 = fmaf(ra.z, w1r[1+jb*4+2], ha2);
      ha3 = fmaf(ra.w, w1r[1+jb*4+3], ha3);
      hb0 = fmaf(rb.x, w1r[1+jb*4+0], hb0);
      hb1 = fmaf(rb.y, w1r[1+jb*4+1], hb1);
      hb2 = fmaf(rb.z, w1r[1+jb*4+2], hb2);
      hb3 = fmaf(rb.w, w1r[1+jb*4+3], hb3);
    }
    float hA = fmaxf((ha0+ha1)+(ha2+ha3), 0.f);
    float hB = fmaxf((hb0+hb1)+(hb2+hb3), 0.f);
    hL[wv][half*2+0][c] = hA;
    hL[wv][half*2+1][c] = hB;

    // ---- w = h @ W2 for both edges; W2 reads amortized over 4 edges ----
    float wa0=0.f,wa1=0.f,wa2=0.f,wa3=0.f,wa4=0.f,wa5=0.f,wa6=0.f;
    float wb0=0.f,wb1=0.f,wb2=0.f,wb3=0.f,wb4=0.f,wb5=0.f,wb6=0.f;
    #pragma unroll
    for (int c4=0;c4<8;c4++){
      float4 ha4 = *(const float4*)&hL[wv][half*2+0][c4*4];
      float4 hb4 = *(const float4*)&hL[wv][half*2+1][c4*4];
      #pragma unroll
      for (int j=0;j<4;j++){
        int ci = c4*4+j;
        float haj = (j==0)?ha4.x:((j==1)?ha4.y:((j==2)?ha4.z:ha4.w));
        float hbj = (j==0)?hb4.x:((j==1)?hb4.y:((j==2)?hb4.z:hb4.w));
        float4 qa = *(const float4*)&W2A[ci*128 + c*4];
        if (FIRST){
          wa0 = fmaf(haj, qa.x, wa0); wa3 = fmaf(haj, qa.y, wa3); wa5 = fmaf(haj, qa.z, wa5);
          wb0 = fmaf(hbj, qa.x, wb0); wb3 = fmaf(hbj, qa.y, wb3); wb5 = fmaf(hbj, qa.z, wb5);
        } else {
          float4 qb = *(const float4*)&W2B[ci*128 + c*4];
          wa0 = fmaf(haj, qa.x, wa0); wa1 = fmaf(haj, qa.y, wa1);
          wa2 = fmaf(haj, qa.z, wa2); wa3 = fmaf(haj, qa.w, wa3);
          wa4 = fmaf(haj, qb.x, wa4); wa5 = fmaf(haj, qb.y, wa5);
          wa6 = fmaf(haj, qb.z, wa6);
          wb0 = fmaf(hbj, qa.x, wb0); wb1 = fmaf(hbj, qa.y, wb1);
          wb2 = fmaf(hbj, qa.z, wb2); wb3 = fmaf(hbj, qa.w, wb3);
          wb4 = fmaf(hbj, qb.x, wb4); wb5 = fmaf(hbj, qb.y, wb5);
          wb6 = fmaf(hbj, qb.z, wb6);
        }
      }
    }

    // ---- messages ----
    float y2aA=ga.y*ga.z, y2bA=ga.z*ga.w, y2cA=3.f*ga.w*ga.w-1.f, y2dA=ga.y*ga.w, y2eA=ga.y*ga.y-ga.z*ga.z;
    float y2aB=gb.y*gb.z, y2bB=gb.z*gb.w, y2cB=3.f*gb.w*gb.w-1.f, y2dB=gb.y*gb.w, y2eB=gb.y*gb.y-gb.z*gb.z;
    float m0A = wa0*ca0;
    float m0B = wb0*cb0;
    if (!FIRST){
      m0A += wa1*(ca1*ga.y+ca2*ga.z+ca3*ga.w)
           + wa2*(ca4*y2aA+ca5*y2bA+ca6*y2cA+ca7*y2dA+ca8*y2eA);
      m0B += wb1*(cb1*gb.y+cb2*gb.z+cb3*gb.w)
           + wb2*(cb4*y2aB+cb5*y2bB+cb6*y2cB+cb7*y2dB+cb8*y2eB);
    }

    // ---- logits: per-lane products + reductions (DPP for xor1/2) ----
    float pa0=m0A*Sa0, pa1=m0A*Sa1, pa2=m0A*Sa2, pa3=m0A*Sa3;
    float pb0=m0B*Sb0, pb1=m0B*Sb1, pb2=m0B*Sb2, pb3=m0B*Sb3;
    pa0 += dppx1(pa0); pa1 += dppx1(pa1); pa2 += dppx1(pa2); pa3 += dppx1(pa3);
    pb0 += dppx1(pb0); pb1 += dppx1(pb1); pb2 += dppx1(pb2); pb3 += dppx1(pb3);
    pa0 += dppx2(pa0); pa1 += dppx2(pa1); pa2 += dppx2(pa2); pa3 += dppx2(pa3);
    pb0 += dppx2(pb0); pb1 += dppx2(pb1); pb2 += dppx2(pb2); pb3 += dppx2(pb3);
    #pragma unroll
    for (int mk=4;mk<32;mk<<=1){
      pa0 += __shfl_xor(pa0,mk,32); pa1 += __shfl_xor(pa1,mk,32);
      pa2 += __shfl_xor(pa2,mk,32); pa3 += __shfl_xor(pa3,mk,32);
      pb0 += __shfl_xor(pb0,mk,32); pb1 += __shfl_xor(pb1,mk,32);
      pb2 += __shfl_xor(pb2,mk,32); pb3 += __shfl_xor(pb3,mk,32);
    }
    float ShA = (hh==0)?pa0:((hh==1)?pa1:((hh==2)?pa2:pa3));
    float ShB = (hh==0)?pb0:((hh==1)?pb1:((hh==2)?pb2:pb3));
    float elA = __expf(ShA * 0.35355339059327373f);
    float elB = __expf(ShB * 0.35355339059327373f);

    // ---- edge A: flush + accumulate ----
    if (dCa != curd){
      if (curd >= 0){
        #pragma unroll
        for (int j=0;j<9;j++) atomicAdd(&aggG[(size_t)curd*288 + j*32 + c], A[j]);
        if ((c&7)==0) atomicAdd(&den[(size_t)curd*4 + hh], denA);
      }
      #pragma unroll
      for (int j=0;j<9;j++) A[j]=0.f;
      denA = 0.f;
      curd = dCa;
    }
    denA += elA;
    A[0] = fmaf(elA, m0A, A[0]);
    A[1] = fmaf(elA, wa3*ca0*ga.y + wa4*ca1, A[1]);
    A[2] = fmaf(elA, wa3*ca0*ga.z + wa4*ca2, A[2]);
    A[3] = fmaf(elA, wa3*ca0*ga.w + wa4*ca3, A[3]);
    A[4] = fmaf(elA, wa5*ca0*y2aA + wa6*ca4, A[4]);
    A[5] = fmaf(elA, wa5*ca0*y2bA + wa6*ca5, A[5]);
    A[6] = fmaf(elA, wa5*ca0*y2cA + wa6*ca6, A[6]);
    A[7] = fmaf(elA, wa5*ca0*y2dA + wa6*ca7, A[7]);
    A[8] = fmaf(elA, wa5*ca0*y2eA + wa6*ca8, A[8]);

    // ---- edge B: flush + accumulate ----
    if (dCb != curd){
      if (curd >= 0){
        #pragma unroll
        for (int j=0;j<9;j++) atomicAdd(&aggG[(size_t)curd*288 + j*32 + c], A[j]);
        if ((c&7)==0) atomicAdd(&den[(size_t)curd*4 + hh], denA);
      }
      #pragma unroll
      for (int j=0;j<9;j++) A[j]=0.f;
      denA = 0.f;
      curd = dCb;
    }
    denA += elB;
    A[0] = fmaf(elB, m0B, A[0]);
    A[1] = fmaf(elB, wb3*cb0*gb.y + wb4*cb1, A[1]);
    A[2] = fmaf(elB, wb3*cb0*gb.z + wb4*cb2, A[2]);
    A[3] = fmaf(elB, wb3*cb0*gb.w + wb4*cb3, A[3]);
    A[4] = fmaf(elB, wb5*cb0*y2aB + wb6*cb4, A[4]);
    A[5] = fmaf(elB, wb5*cb0*y2bB + wb6*cb5, A[5]);
    A[6] = fmaf(elB, wb5*cb0*y2cB + wb6*cb6, A[6]);
    A[7] = fmaf(elB, wb5*cb0*y2dB + wb6*cb7, A[7]);
    A[8] = fmaf(elB, wb5*cb0*y2eB + wb6*cb8, A[8]);
  }
  if (curd >= 0){
    #pragma unroll
    for (int j=0;j<9;j++) atomicAdd(&aggG[(size_t)curd*288 + j*32 + c], A[j]);
    if ((c&7)==0) atomicAdd(&den[(size_t)curd*4 + hh], denA);
  }
}

// ---------- node update ----------
__global__ __launch_bounds__(256) void k_update(
    const float* __restrict__ aggG, const float* __restrict__ f_in,
    const float* __restrict__ den,
    const float* __restrict__ Ws0, const float* __restrict__ Ws1,
    const float* __restrict__ Ws2, const float* __restrict__ Wsk,
    float* __restrict__ f_out)
{
  __shared__ float wL[4096];
  __shared__ float agL[8][297];
  __shared__ float f0L[8][33];
  __shared__ float dL[8][4];
  int tid = threadIdx.x;
  int nb = blockIdx.x*8;
  for (int i=tid;i<1024;i+=256){
    wL[i]=Ws0[i]; wL[1024+i]=Ws1[i]; wL[2048+i]=Ws2[i]; wL[3072+i]=Wsk[i];
  }
  if (tid < 32){
    int nl = tid>>2, hd = tid&3;
    dL[nl][hd] = 1.f/(den[(size_t)(nb+nl)*4 + hd] + 1e-30f);
  }
  { int nl=tid>>5, cc=tid&31; f0L[nl][cc] = f_in[(size_t)(nb+nl)*288 + cc]; }
  __syncthreads();
  for (int i=tid;i<2304;i+=256){
    int nl=i/288, F=i-nl*288, r=F>>5, cc=F&31;
    agL[nl][r*33+cc] = aggG[(size_t)(nb+nl)*288 + F] * dL[nl][cc>>3];
  }
  __syncthreads();
  int nl = tid>>5, o = tid&31;
  size_t obase = (size_t)(nb+nl)*288;
  #pragma unroll 1
  for (int r=0;r<9;r++){
    const float* W = (r==0)? wL : ((r<4)? wL+1024 : wL+2048);
    float acc=0.f;
    #pragma unroll
    for (int cc=0;cc<32;cc++) acc = fmaf(agL[nl][r*33+cc], W[cc*32+o], acc);
    if (r==0){
      #pragma unroll
      for (int cc=0;cc<32;cc++) acc = fmaf(f0L[nl][cc], wL[3072 + cc*32+o], acc);
    }
    f_out[obase + r*32 + o] = acc;
  }
}

// ---------- output head (f32 out) ----------
__global__ __launch_bounds__(256) void k_out(
    const float* __restrict__ f_in, const float* __restrict__ Wout,
    const float* __restrict__ Wc, float* __restrict__ out)
{
  __shared__ float sh[8][33];
  int tid = threadIdx.x;
  int nl = tid>>5, c = tid&31;
  int n = blockIdx.x*8 + nl;
  const float* f0 = f_in + (size_t)n*288;
  float acc=0.f;
  #pragma unroll
  for (int ci=0;ci<32;ci++) acc = fmaf(f0[ci], Wout[ci*32+c], acc);
  out[(size_t)n*32 + c] = acc;
  sh[nl][c] = acc;
  __syncthreads();
  if (tid < 120){
    int nl2 = tid/15, j = tid%15;
    int n2 = blockIdx.x*8 + nl2;
    float a = 0.f;
    #pragma unroll
    for (int ci=0;ci<32;ci++) a = fmaf(sh[nl2][ci], Wc[ci*15+j], a);
    out[(size_t)NN*32 + (size_t)n2*15 + j] = a;
  }
}

extern "C" void kernel_launch(void* const* d_in, const int* in_sizes, int n_in,
                              void* d_out, int out_size, void* d_ws, size_t ws_size,
                              hipStream_t stream)
{
  (void)in_sizes; (void)n_in;
  const float* pos       = (const float*)d_in[0];
  const float* node_l0   = (const float*)d_in[1];
  const float* edge_feat = (const float*)d_in[2];
  const int* esrc = (const int*)d_in[3];
  const int* edst = (const int*)d_in[4];
  const float* Wr1  = (const float*)d_in[5];
  const float* br1  = (const float*)d_in[6];
  const float* Wr2  = (const float*)d_in[7];
  const float* Wq   = (const float*)d_in[8];
  const float* Wk   = (const float*)d_in[9];
  const float* Ws0  = (const float*)d_in[10];
  const float* Ws1  = (const float*)d_in[11];
  const float* Ws2  = (const float*)d_in[12];
  const float* Wsk  = (const float*)d_in[13];
  const float* Wout = (const float*)d_in[14];
  const float* Wc   = (const float*)d_in[15];

  char* ws = (char*)d_ws;
  size_t off = 0;
  auto take = [&](size_t bytes)->char*{
    char* p = ws + off;
    off += (bytes + 255) & ~(size_t)255;
    return p;
  };
  float* fA      = (float*)take((size_t)NN*288*4);
  float* fB      = (float*)take((size_t)NN*288*4);
  float* Tq      = (float*)take((size_t)NN*128*4);
  int*   hist    = (int*)  take((size_t)NN*4);
  int*   offs    = (int*)  take((size_t)(NN+1)*4);
  int*   cursor  = (int*)  take((size_t)NN*4);
  int*   perm    = (int*)  take((size_t)EE*4);
  float* den     = (float*)take((size_t)NN*4*4);
  size_t need = off;                                  // ~88 MB

  if (ws_size < need){
    k_zero<<<(out_size+255)/256,256,0,stream>>>((float*)d_out, out_size);
    return;
  }

  k_init<<<33750,256,0,stream>>>(node_l0, fA, hist);
  k_hist<<<1875,256,0,stream>>>(edst, hist);
  k_scan<<<1,1024,0,stream>>>(hist, offs, cursor, NN);
  k_scatter<<<1875,256,0,stream>>>(edst, cursor, perm);

  float* fi = fA; float* fo = fB;
  for (int l=0; l<2; ++l){
    k_zeroagg<<<33750,256,0,stream>>>(fo, den);
    k_qt<<<3750,256,0,stream>>>(fi, Wq + l*1024, Wk + l*1024, Tq);
    if (l==0){
      k_fused<1><<<7500,256,0,stream>>>(pos, edge_feat, esrc, edst, perm,
          fi, Tq, Wr1 + l*1056, br1 + l*32, Wr2 + l*7168,
          fo, den);
    } else {
      k_fused<0><<<7500,256,0,stream>>>(pos, edge_feat, esrc, edst, perm,
          fi, Tq, Wr1 + l*1056, br1 + l*32, Wr2 + l*7168,
          fo, den);
    }
    k_update<<<3750,256,0,stream>>>(fo, fi, den,
        Ws0 + l*1024, Ws1 + l*1024, Ws2 + l*1024, Wsk + l*1024, fo);
    float* tmp = fi; fi = fo; fo = tmp;
  }
  k_out<<<3750,256,0,stream>>>(fi, Wout, Wc, (float*)d_out);
}